// Round 7
// baseline (1243.110 us; speedup 1.0000x reference)
//
#include <hip/hip_runtime.h>
#include <hip/hip_bf16.h>

#define LL 128
#define BB 128
#define AA 512
#define II 512
#define HH 1024
#define GG 4096   // 4*H
#define KK 1024   // I+A == H
#define TEAMS 4   // 4 teams x 32 batches
#define DG 64     // 64 dim-groups x 16 dims
#define NBLK (TEAMS * DG)   // 256 blocks

typedef __attribute__((ext_vector_type(8))) short short8;
typedef __attribute__((ext_vector_type(4))) float f32x4;
typedef __attribute__((ext_vector_type(4))) unsigned uint32x4;

static __device__ __forceinline__ unsigned short f2b(float x) {
    union { float f; unsigned u; } v; v.f = x;
    unsigned r = v.u + 0x7fffu + ((v.u >> 16) & 1u);
    return (unsigned short)(r >> 16);
}
static __device__ __forceinline__ float b2f(unsigned short b) {
    union { unsigned u; float f; } v; v.u = ((unsigned)b) << 16; return v.f;
}
static __device__ __forceinline__ float fast_sigmoid(float x) {
    return 1.f / (1.f + __expf(-x));
}
static __device__ __forceinline__ float fast_tanh(float x) {
    float e = __expf(2.f * x);
    return (e - 1.f) / (e + 1.f);
}

typedef const __attribute__((address_space(1))) unsigned char ga_u8;
typedef __attribute__((address_space(3))) unsigned char ls_u8;
static __device__ __forceinline__ void gload_lds16(void* lds_base, const void* gsrc) {
    __builtin_amdgcn_global_load_lds((ga_u8*)gsrc, (ls_u8*)lds_base, 16, 0, 0);
}

// device-coherent UC accesses (proven in round 4): bypass L1+L2, served at coherence point
static __device__ __forceinline__ short8 uc_load128(const unsigned short* p) {
    short8 r;
    asm volatile("global_load_dwordx4 %0, %1, off sc0 sc1" : "=v"(r) : "v"(p));
    return r;
}
static __device__ __forceinline__ void uc_store128(unsigned short* p, uint32x4 v) {
    asm volatile("global_store_dwordx4 %0, %1, off sc0 sc1" :: "v"(p), "v"(v) : "memory");
}
static __device__ __forceinline__ unsigned uc_flag_load(const unsigned int* p) {
    unsigned fv;
    asm volatile("global_load_dword %0, %1, off sc0 sc1\n\ts_waitcnt vmcnt(0)"
                 : "=v"(fv) : "v"(p) : "memory");
    return fv;
}
static __device__ __forceinline__ void uc_flag_store(unsigned int* p, unsigned v) {
    asm volatile("global_store_dword %0, %1, off sc0 sc1" :: "v"(p), "v"(v) : "memory");
}

// ---------------- pack kernels ----------------
__global__ void build_x_kernel(const float* __restrict__ act, const float* __restrict__ inF,
                               unsigned short* __restrict__ xb) {
    int stride = gridDim.x * blockDim.x;
    for (int idx = blockIdx.x * blockDim.x + threadIdx.x; idx < LL * BB * KK; idx += stride) {
        int i  = idx & (KK - 1);
        int lb = idx >> 10;
        float v;
        if (i < II) v = inF[(lb & (BB - 1)) * II + i];
        else        v = act[(size_t)lb * AA + (i - II)];
        xb[idx] = f2b(v);
    }
}

__global__ void cast_kernel(const float* __restrict__ s, unsigned short* __restrict__ d, int n) {
    int stride = gridDim.x * blockDim.x;
    for (int i = blockIdx.x * blockDim.x + threadIdx.x; i < n; i += stride) d[i] = f2b(s[i]);
}

// ---------------- phase 1: gates_x = xb @ W_ih^T (bf16 out) ----------------
__launch_bounds__(256)
__global__ void gemm_x_kernel(const unsigned short* __restrict__ Ab,
                              const unsigned short* __restrict__ Bb,
                              unsigned short* __restrict__ Cb) {
    __shared__ __attribute__((aligned(16))) unsigned short As[128 * 32];
    __shared__ __attribute__((aligned(16))) unsigned short Bs[128 * 32];
    const int tid  = threadIdx.x;
    const int lane = tid & 63;
    const int wid  = tid >> 6;
    const int wr = wid >> 1, wc = wid & 1;
    const int m0 = blockIdx.x * 128, n0 = blockIdx.y * 128;
    const int lrow = lane & 15, lko = (lane >> 4) * 8;
    f32x4 acc[4][4] = {};

    for (int kt = 0; kt < KK / 32; ++kt) {
        const int k0 = kt * 32;
        #pragma unroll
        for (int t = 0; t < 2; ++t) {
            int q   = t * 256 + tid;
            int row = q >> 2;
            int co  = (q & 3) * 8;
            gload_lds16(&As[(t * 256 + wid * 64) * 8], &Ab[(size_t)(m0 + row) * KK + k0 + co]);
            gload_lds16(&Bs[(t * 256 + wid * 64) * 8], &Bb[(size_t)(n0 + row) * KK + k0 + co]);
        }
        __syncthreads();
        short8 af[4], bf[4];
        #pragma unroll
        for (int mi = 0; mi < 4; ++mi)
            af[mi] = *(const short8*)&As[(wr * 64 + mi * 16 + lrow) * 32 + lko];
        #pragma unroll
        for (int ni = 0; ni < 4; ++ni)
            bf[ni] = *(const short8*)&Bs[(wc * 64 + ni * 16 + lrow) * 32 + lko];
        #pragma unroll
        for (int mi = 0; mi < 4; ++mi)
            #pragma unroll
            for (int ni = 0; ni < 4; ++ni)
                acc[mi][ni] = __builtin_amdgcn_mfma_f32_16x16x32_bf16(af[mi], bf[ni], acc[mi][ni], 0, 0, 0);
        __syncthreads();
    }
    #pragma unroll
    for (int mi = 0; mi < 4; ++mi) {
        #pragma unroll
        for (int ni = 0; ni < 4; ++ni) {
            int col = n0 + wc * 64 + ni * 16 + lrow;
            #pragma unroll
            for (int r = 0; r < 4; ++r) {
                int row = m0 + wr * 64 + mi * 16 + (lane >> 4) * 4 + r;
                Cb[(size_t)row * GG + col] = f2b(acc[mi][ni][r]);
            }
        }
    }
}

// ---------------- phase 2: persistent LSTM recurrence (round-4 protocol, distributed flags) ----
// 256 blocks = 4 teams (32 batches) x 64 dim-groups (16 dims). W_hh slice in LDS
// (128 KB, forces 1 block/CU). 8 waves = 2 M-tiles x 4 K-slices. Cross-block h
// exchange via device-coherent UC (sc0 sc1) — proven in round 4. Sync: per-dg
// flags; wave (mt,ks) polls the 16 producers of its K-slice; the 8 waves
// collectively cover all 64 dgs and sync2 joins them, so the h-store at step l
// happens only after every team block finished its step-(l-1) reads -> the
// 2-buffer ping-pong is race-free. No contended atomic counter anywhere.
__launch_bounds__(512)
__global__ void lstm_kernel(const unsigned short* __restrict__ gx,   // [L*B][4096] bf16
                            const float* __restrict__ Whh,           // [4096][1024] f32
                            const float* __restrict__ bih,
                            const float* __restrict__ bhh,
                            const float* __restrict__ c0,            // [B][H] f32
                            unsigned short* __restrict__ hb,         // [2][B][H] bf16
                            unsigned int* __restrict__ flagsG,       // [TEAMS*DG] zeroed
                            float* __restrict__ out) {               // hs | h_n | c_n
    __shared__ __attribute__((aligned(16))) unsigned short wlds[4 * 32 * 64 * 8]; // 128 KB
    __shared__ float red[2 * 3 * 64 * 17];                                        // ~26 KB
    __shared__ __attribute__((aligned(16))) unsigned short hbuf[32 * 16];         // 1 KB

    const int tid  = threadIdx.x;
    const int lane = tid & 63;
    const int w    = tid >> 6;          // 8 waves
    const int mt   = w >> 2;            // M-tile (16 batches)
    const int ks   = w & 3;             // K-slice (256)
    const int dg   = blockIdx.x & (DG - 1);
    const int mg   = blockIdx.x >> 6;   // team
    const int j0   = dg * 16;
    const int d    = lane & 15;
    const int rg   = lane >> 4;

    // pack W_hh slice [4 gates][16 dims] into B-fragment order (once)
    for (int idx = w; idx < 4 * 32; idx += 8) {
        int t = idx >> 5, kt = idx & 31;
        const float* src = &Whh[(size_t)(t * HH + j0 + d) * HH + kt * 32 + rg * 8];
        unsigned short* dst = &wlds[(idx * 64 + lane) * 8];
        #pragma unroll
        for (int j = 0; j < 8; ++j) dst[j] = f2b(src[j]);
    }
    float bias_r[4], c_r[4];
    const int brow = mg * 32 + mt * 16 + rg * 4;   // first batch of this thread's quad
    #pragma unroll
    for (int t = 0; t < 4; ++t) bias_r[t] = bih[t * HH + j0 + d] + bhh[t * HH + j0 + d];
    #pragma unroll
    for (int r = 0; r < 4; ++r) c_r[r] = c0[(brow + r) * HH + j0 + d];
    __syncthreads();

    const unsigned int* myflag = flagsG + mg * DG + ks * 16 + d;   // this wave's 16 producers
    unsigned int*       ourflag = flagsG + mg * DG + dg;

    for (int l = 0; l < LL; ++l) {
        const unsigned short* hr = hb + (size_t)(l & 1) * (BB * HH);
        unsigned short*       hw = hb + (size_t)((l + 1) & 1) * (BB * HH);

        // gx prefetch (cached; only gate-math waves use it) — overlaps the poll
        float gxv[4][4];
        if (ks == 0) {
            #pragma unroll
            for (int r = 0; r < 4; ++r) {
                const unsigned short* gp = &gx[((size_t)l * BB + (brow + r)) * GG + j0 + d];
                #pragma unroll
                for (int t = 0; t < 4; ++t) gxv[r][t] = b2f(gp[t * HH]);
            }
        }

        // wait for this wave's 16 producer blocks (dims ks*256..+256)
        if (l > 0) {
            unsigned fv; int guard = 0;
            do { fv = uc_flag_load(myflag); }
            while (__any(fv < (unsigned)l) && ++guard < (1 << 18));
        }

        // coherent h read: 8 wide UC loads per lane (16 rows x 256 K per wave)
        short8 af[8];
        const unsigned short* hp = hr + (size_t)(mg * 32 + mt * 16 + d) * HH + ks * 256 + rg * 8;
        #pragma unroll
        for (int j = 0; j < 8; ++j) af[j] = uc_load128(hp + j * 32);
        asm volatile("s_waitcnt vmcnt(0)" ::: "memory");
        __builtin_amdgcn_sched_barrier(0);

        f32x4 acc[4] = {};
        #pragma unroll
        for (int j = 0; j < 8; ++j) {
            #pragma unroll
            for (int t = 0; t < 4; ++t) {
                short8 bfr = *(const short8*)&wlds[((t * 32 + ks * 8 + j) * 64 + lane) * 8];
                acc[t] = __builtin_amdgcn_mfma_f32_16x16x32_bf16(af[j], bfr, acc[t], 0, 0, 0);
            }
        }

        // single-round cross-wave K reduction: ks 1..3 write, sync, ks 0 absorbs
        if (ks != 0) {
            float* sp = &red[(size_t)((mt * 3 + (ks - 1)) * 64 + lane) * 17];
            #pragma unroll
            for (int t = 0; t < 4; ++t)
                #pragma unroll
                for (int r = 0; r < 4; ++r) sp[t * 4 + r] = acc[t][r];
        }
        __syncthreads();   // sync1: partials ready

        if (ks == 0) {
            #pragma unroll
            for (int s = 0; s < 3; ++s) {
                const float* sp = &red[(size_t)((mt * 3 + s) * 64 + lane) * 17];
                #pragma unroll
                for (int t = 0; t < 4; ++t)
                    #pragma unroll
                    for (int r = 0; r < 4; ++r) acc[t][r] += sp[t * 4 + r];
            }
            #pragma unroll
            for (int r = 0; r < 4; ++r) {
                float gi = acc[0][r] + gxv[r][0] + bias_r[0];
                float gf = acc[1][r] + gxv[r][1] + bias_r[1];
                float gg = acc[2][r] + gxv[r][2] + bias_r[2];
                float go = acc[3][r] + gxv[r][3] + bias_r[3];
                float ig = fast_sigmoid(gi);
                float fg = fast_sigmoid(gf);
                float og = fast_sigmoid(go);
                float gt = fast_tanh(gg);
                float c1 = fg * c_r[r] + ig * gt;
                float h1 = og * fast_tanh(c1);
                c_r[r] = c1;
                hbuf[(mt * 16 + rg * 4 + r) * 16 + d] = f2b(h1);
                out[((size_t)l * BB + (brow + r)) * HH + j0 + d] = h1;
                if (l == LL - 1) {
                    out[(size_t)LL * BB * HH + (brow + r) * HH + j0 + d] = h1;
                    out[(size_t)LL * BB * HH + BB * HH + (brow + r) * HH + j0 + d] = c1;
                }
            }
        }
        __syncthreads();   // sync2: hbuf ready, red consumed, all polls passed

        // wave 2 (non-gate wave: no out-stores in flight): h store + own flag
        if (w == 2) {
            int row = lane >> 1, half = lane & 1;
            uint32x4 hv = *(const uint32x4*)&hbuf[row * 16 + half * 8];
            uc_store128(&hw[(size_t)(mg * 32 + row) * HH + j0 + half * 8], hv);
            asm volatile("s_waitcnt vmcnt(0)" ::: "memory");   // h acked at coherence point
            if (lane == 0) uc_flag_store(ourflag, (unsigned)(l + 1));
        }
        // no end-of-step block barrier needed: next step's poll + sync2 order everything
    }
}

extern "C" void kernel_launch(void* const* d_in, const int* in_sizes, int n_in,
                              void* d_out, int out_size, void* d_ws, size_t ws_size,
                              hipStream_t stream) {
    const float* act = (const float*)d_in[0];
    const float* inF = (const float*)d_in[1];
    const float* h0  = (const float*)d_in[2];
    const float* c0  = (const float*)d_in[3];
    const float* Wih = (const float*)d_in[4];
    const float* Whh = (const float*)d_in[5];
    const float* bih = (const float*)d_in[6];
    const float* bhh = (const float*)d_in[7];
    float* out = (float*)d_out;

    char* p = (char*)d_ws;
    unsigned short* xb    = (unsigned short*)p; p += (size_t)LL * BB * KK * 2;   // 33.5 MB
    unsigned short* wih_b = (unsigned short*)p; p += (size_t)GG * KK * 2;        //  8.4 MB
    unsigned short* hb    = (unsigned short*)p; p += (size_t)2 * BB * HH * 2;    //  0.5 MB
    unsigned short* gx    = (unsigned short*)p; p += (size_t)LL * BB * GG * 2;   // 134 MB
    unsigned int*   flags = (unsigned int*)p;   p += TEAMS * DG * sizeof(unsigned int);

    hipMemsetAsync(flags, 0, TEAMS * DG * sizeof(unsigned int), stream);
    build_x_kernel<<<dim3(2048), dim3(256), 0, stream>>>(act, inF, xb);
    cast_kernel<<<dim3(1024), dim3(256), 0, stream>>>(Wih, wih_b, GG * KK);
    cast_kernel<<<dim3(64), dim3(256), 0, stream>>>(h0, hb, BB * HH);
    gemm_x_kernel<<<dim3(128, 32), dim3(256), 0, stream>>>(xb, wih_b, gx);

    void* args[] = { (void*)&gx, (void*)&Whh, (void*)&bih, (void*)&bhh,
                     (void*)&c0, (void*)&hb, (void*)&flags, (void*)&out };
    hipLaunchCooperativeKernel((const void*)lstm_kernel, dim3(NBLK), dim3(512), args, 0, stream);
}

// Round 8
// 949.675 us; speedup vs baseline: 1.3090x; 1.3090x over previous
//
#include <hip/hip_runtime.h>
#include <hip/hip_bf16.h>

#define LL 128
#define BB 128
#define AA 512
#define II 512
#define HH 1024
#define GG 4096   // 4*H
#define KK 1024   // I+A == H
#define NTEAM 8   // 8 teams x 16 batches
#define NDG 32    // 32 dim-groups x 32 dims
#define NBLK (NTEAM * NDG)   // 256 blocks

typedef __attribute__((ext_vector_type(8))) short short8;
typedef __attribute__((ext_vector_type(4))) float f32x4;
typedef __attribute__((ext_vector_type(4))) unsigned uint32x4;

static __device__ __forceinline__ unsigned short f2b(float x) {
    union { float f; unsigned u; } v; v.f = x;
    unsigned r = v.u + 0x7fffu + ((v.u >> 16) & 1u);
    return (unsigned short)(r >> 16);
}
static __device__ __forceinline__ float b2f(unsigned short b) {
    union { unsigned u; float f; } v; v.u = ((unsigned)b) << 16; return v.f;
}
static __device__ __forceinline__ float fast_sigmoid(float x) {
    return 1.f / (1.f + __expf(-x));
}
static __device__ __forceinline__ float fast_tanh(float x) {
    float e = __expf(2.f * x);
    return (e - 1.f) / (e + 1.f);
}

typedef const __attribute__((address_space(1))) unsigned char ga_u8;
typedef __attribute__((address_space(3))) unsigned char ls_u8;
static __device__ __forceinline__ void gload_lds16(void* lds_base, const void* gsrc) {
    __builtin_amdgcn_global_load_lds((ga_u8*)gsrc, (ls_u8*)lds_base, 16, 0, 0);
}

// device-coherent UC accesses (proven rounds 4/7): bypass L1+L2, served at coherence point
static __device__ __forceinline__ short8 uc_load128(const unsigned short* p) {
    short8 r;
    asm volatile("global_load_dwordx4 %0, %1, off sc0 sc1" : "=v"(r) : "v"(p));
    return r;
}
static __device__ __forceinline__ void uc_store128(unsigned short* p, uint32x4 v) {
    asm volatile("global_store_dwordx4 %0, %1, off sc0 sc1" :: "v"(p), "v"(v) : "memory");
}
static __device__ __forceinline__ unsigned uc_flag_load(const unsigned int* p) {
    unsigned fv;
    asm volatile("global_load_dword %0, %1, off sc0 sc1\n\ts_waitcnt vmcnt(0)"
                 : "=v"(fv) : "v"(p) : "memory");
    return fv;
}
static __device__ __forceinline__ void uc_flag_store(unsigned int* p, unsigned v) {
    asm volatile("global_store_dword %0, %1, off sc0 sc1" :: "v"(p), "v"(v) : "memory");
}

// ---------------- pack kernels ----------------
__global__ void build_x_kernel(const float* __restrict__ act, const float* __restrict__ inF,
                               unsigned short* __restrict__ xb) {
    int stride = gridDim.x * blockDim.x;
    for (int idx = blockIdx.x * blockDim.x + threadIdx.x; idx < LL * BB * KK; idx += stride) {
        int i  = idx & (KK - 1);
        int lb = idx >> 10;
        float v;
        if (i < II) v = inF[(lb & (BB - 1)) * II + i];
        else        v = act[(size_t)lb * AA + (i - II)];
        xb[idx] = f2b(v);
    }
}

__global__ void cast_kernel(const float* __restrict__ s, unsigned short* __restrict__ d, int n) {
    int stride = gridDim.x * blockDim.x;
    for (int i = blockIdx.x * blockDim.x + threadIdx.x; i < n; i += stride) d[i] = f2b(s[i]);
}

// ---------------- phase 1: gates_x = xb @ W_ih^T (bf16 out) ----------------
__launch_bounds__(256)
__global__ void gemm_x_kernel(const unsigned short* __restrict__ Ab,
                              const unsigned short* __restrict__ Bb,
                              unsigned short* __restrict__ Cb) {
    __shared__ __attribute__((aligned(16))) unsigned short As[128 * 32];
    __shared__ __attribute__((aligned(16))) unsigned short Bs[128 * 32];
    const int tid  = threadIdx.x;
    const int lane = tid & 63;
    const int wid  = tid >> 6;
    const int wr = wid >> 1, wc = wid & 1;
    const int m0 = blockIdx.x * 128, n0 = blockIdx.y * 128;
    const int lrow = lane & 15, lko = (lane >> 4) * 8;
    f32x4 acc[4][4] = {};

    for (int kt = 0; kt < KK / 32; ++kt) {
        const int k0 = kt * 32;
        #pragma unroll
        for (int t = 0; t < 2; ++t) {
            int q   = t * 256 + tid;
            int row = q >> 2;
            int co  = (q & 3) * 8;
            gload_lds16(&As[(t * 256 + wid * 64) * 8], &Ab[(size_t)(m0 + row) * KK + k0 + co]);
            gload_lds16(&Bs[(t * 256 + wid * 64) * 8], &Bb[(size_t)(n0 + row) * KK + k0 + co]);
        }
        __syncthreads();
        short8 af[4], bf[4];
        #pragma unroll
        for (int mi = 0; mi < 4; ++mi)
            af[mi] = *(const short8*)&As[(wr * 64 + mi * 16 + lrow) * 32 + lko];
        #pragma unroll
        for (int ni = 0; ni < 4; ++ni)
            bf[ni] = *(const short8*)&Bs[(wc * 64 + ni * 16 + lrow) * 32 + lko];
        #pragma unroll
        for (int mi = 0; mi < 4; ++mi)
            #pragma unroll
            for (int ni = 0; ni < 4; ++ni)
                acc[mi][ni] = __builtin_amdgcn_mfma_f32_16x16x32_bf16(af[mi], bf[ni], acc[mi][ni], 0, 0, 0);
        __syncthreads();
    }
    #pragma unroll
    for (int mi = 0; mi < 4; ++mi) {
        #pragma unroll
        for (int ni = 0; ni < 4; ++ni) {
            int col = n0 + wc * 64 + ni * 16 + lrow;
            #pragma unroll
            for (int r = 0; r < 4; ++r) {
                int row = m0 + wr * 64 + mi * 16 + (lane >> 4) * 4 + r;
                Cb[(size_t)row * GG + col] = f2b(acc[mi][ni][r]);
            }
        }
    }
}

// ---------------- phase 2: persistent LSTM recurrence ----------------
// 256 blocks = 8 teams (16 batches) x 32 dim-groups (32 dims). W_hh slice
// (4 gates x 32 dims x K=1024 = 256 KB bf16) lives in REGISTERS (128 VGPR/thr).
// 8 waves = 2 dim-halves x 4 K-slices(256). Cross-block h exchange: UC sc0 sc1
// (proven). Sync: per-dg flags; ONE poller wave per block (wave 7) checks all
// 32 team flags with a single wave-wide UC load per spin, then __syncthreads
// gates the block. Producer's flag(l+1) is set after its h_{l+1} store is
// acked AND after its own reads of h_l -> poll(l) passing implies all blocks
// finished reading h_{l-1}, so overwriting buf[(l+1)&1] is race-free.
__launch_bounds__(512, 2)
__global__ void lstm_kernel(const unsigned short* __restrict__ gx,   // [L*B][4096] bf16
                            const float* __restrict__ Whh,           // [4096][1024] f32
                            const float* __restrict__ bih,
                            const float* __restrict__ bhh,
                            const float* __restrict__ c0,            // [B][H] f32
                            unsigned short* __restrict__ hb,         // [2][B][H] bf16
                            unsigned int* __restrict__ flagsG,       // [NTEAM*NDG] zeroed
                            float* __restrict__ out) {               // hs | h_n | c_n
    __shared__ float red[2 * 3 * 64 * 17];                                   // ~26 KB
    __shared__ __attribute__((aligned(16))) unsigned short hbuf[16 * 32];    // 1 KB

    const int tid  = threadIdx.x;
    const int lane = tid & 63;
    const int w    = tid >> 6;          // 8 waves
    const int nq   = w >> 2;            // dim-half (16 dims)
    const int ksl  = w & 3;             // K-slice (256)
    const int dg   = blockIdx.x & (NDG - 1);
    const int mg   = blockIdx.x >> 5;   // team
    const int j0   = dg * 32;
    const int b0   = mg * 16;
    const int d    = lane & 15;
    const int rg   = lane >> 4;

    // W_hh slice into registers, B-fragment order:
    // breg[t][kf]: lane holds W[t*H + j0 + nq*16 + d][ksl*256 + kf*32 + rg*8 .. +8]
    short8 breg[4][8];
    #pragma unroll
    for (int t = 0; t < 4; ++t) {
        #pragma unroll
        for (int kf = 0; kf < 8; ++kf) {
            const float* src = &Whh[(size_t)(t * HH + j0 + nq * 16 + d) * HH + ksl * 256 + kf * 32 + rg * 8];
            short8 v;
            #pragma unroll
            for (int j = 0; j < 8; ++j) v[j] = (short)f2b(src[j]);
            breg[t][kf] = v;
        }
    }

    float bias_r[4], c_r[4];
    if (ksl == 0) {
        #pragma unroll
        for (int t = 0; t < 4; ++t)
            bias_r[t] = bih[t * HH + j0 + nq * 16 + d] + bhh[t * HH + j0 + nq * 16 + d];
        #pragma unroll
        for (int r = 0; r < 4; ++r) c_r[r] = c0[(b0 + rg * 4 + r) * HH + j0 + nq * 16 + d];
    }

    unsigned int*       ourflag  = flagsG + mg * NDG + dg;
    const unsigned int* pollflag = flagsG + mg * NDG + (lane & 31);

    for (int l = 0; l < LL; ++l) {
        const unsigned short* hr = hb + (size_t)(l & 1) * (BB * HH);
        unsigned short*       hw = hb + (size_t)((l + 1) & 1) * (BB * HH);

        // gx prefetch (cached; gate-math waves only) — overlaps the poll wait
        float gxv[4][4];
        if (ksl == 0) {
            #pragma unroll
            for (int r = 0; r < 4; ++r) {
                const unsigned short* gp = &gx[((size_t)l * BB + (b0 + rg * 4 + r)) * GG + j0 + nq * 16 + d];
                #pragma unroll
                for (int t = 0; t < 4; ++t) gxv[r][t] = b2f(gp[t * HH]);
            }
        }

        // single-poller: wave 7, one wave-wide UC load of all 32 team flags per spin
        if (l > 0 && w == 7) {
            unsigned fv; int guard = 0;
            do { fv = uc_flag_load(pollflag); }
            while (__any(fv < (unsigned)l) && ++guard < (1 << 18));
        }
        __syncthreads();   // releases all waves once flags are seen

        // coherent h read: 8 wide UC loads per lane (16 batches x 256 K per wave)
        short8 af[8];
        const unsigned short* hp = hr + (size_t)(b0 + d) * HH + ksl * 256 + rg * 8;
        #pragma unroll
        for (int kf = 0; kf < 8; ++kf) af[kf] = uc_load128(hp + kf * 32);
        asm volatile("s_waitcnt vmcnt(0)" ::: "memory");
        __builtin_amdgcn_sched_barrier(0);

        f32x4 acc[4] = {};
        #pragma unroll
        for (int kf = 0; kf < 8; ++kf)
            #pragma unroll
            for (int t = 0; t < 4; ++t)
                acc[t] = __builtin_amdgcn_mfma_f32_16x16x32_bf16(af[kf], breg[t][kf], acc[t], 0, 0, 0);

        // single-round cross-wave K reduction: ksl 1..3 write, sync, ksl 0 absorbs
        if (ksl != 0) {
            float* sp = &red[(size_t)((nq * 3 + (ksl - 1)) * 64 + lane) * 17];
            #pragma unroll
            for (int t = 0; t < 4; ++t)
                #pragma unroll
                for (int r = 0; r < 4; ++r) sp[t * 4 + r] = acc[t][r];
        }
        __syncthreads();   // sync1: partials ready

        if (ksl == 0) {
            #pragma unroll
            for (int s = 0; s < 3; ++s) {
                const float* sp = &red[(size_t)((nq * 3 + s) * 64 + lane) * 17];
                #pragma unroll
                for (int t = 0; t < 4; ++t)
                    #pragma unroll
                    for (int r = 0; r < 4; ++r) acc[t][r] += sp[t * 4 + r];
            }
            #pragma unroll
            for (int r = 0; r < 4; ++r) {
                float gi = acc[0][r] + gxv[r][0] + bias_r[0];
                float gf = acc[1][r] + gxv[r][1] + bias_r[1];
                float gg = acc[2][r] + gxv[r][2] + bias_r[2];
                float go = acc[3][r] + gxv[r][3] + bias_r[3];
                float ig = fast_sigmoid(gi);
                float fg = fast_sigmoid(gf);
                float og = fast_sigmoid(go);
                float gt = fast_tanh(gg);
                float c1 = fg * c_r[r] + ig * gt;
                float h1 = og * fast_tanh(c1);
                c_r[r] = c1;
                hbuf[(rg * 4 + r) * 32 + nq * 16 + d] = f2b(h1);
                out[((size_t)l * BB + (b0 + rg * 4 + r)) * HH + j0 + nq * 16 + d] = h1;
                if (l == LL - 1) {
                    out[(size_t)LL * BB * HH + (b0 + rg * 4 + r) * HH + j0 + nq * 16 + d] = h1;
                    out[(size_t)LL * BB * HH + BB * HH + (b0 + rg * 4 + r) * HH + j0 + nq * 16 + d] = c1;
                }
            }
        }
        __syncthreads();   // sync2: hbuf ready, red consumed

        // wave 2 (non-gate): line-dense h store (16 batches x 64 B) + flag
        if (w == 2) {
            int row = lane >> 2, ch = lane & 3;
            uint32x4 hv = *(const uint32x4*)&hbuf[row * 32 + ch * 8];
            uc_store128(&hw[(size_t)(b0 + row) * HH + j0 + ch * 8], hv);
            asm volatile("s_waitcnt vmcnt(0)" ::: "memory");   // acked at coherence point
            if (lane == 0) uc_flag_store(ourflag, (unsigned)(l + 1));
        }
    }
}

extern "C" void kernel_launch(void* const* d_in, const int* in_sizes, int n_in,
                              void* d_out, int out_size, void* d_ws, size_t ws_size,
                              hipStream_t stream) {
    const float* act = (const float*)d_in[0];
    const float* inF = (const float*)d_in[1];
    const float* h0  = (const float*)d_in[2];
    const float* c0  = (const float*)d_in[3];
    const float* Wih = (const float*)d_in[4];
    const float* Whh = (const float*)d_in[5];
    const float* bih = (const float*)d_in[6];
    const float* bhh = (const float*)d_in[7];
    float* out = (float*)d_out;

    char* p = (char*)d_ws;
    unsigned short* xb    = (unsigned short*)p; p += (size_t)LL * BB * KK * 2;   // 33.5 MB
    unsigned short* wih_b = (unsigned short*)p; p += (size_t)GG * KK * 2;        //  8.4 MB
    unsigned short* hb    = (unsigned short*)p; p += (size_t)2 * BB * HH * 2;    //  0.5 MB
    unsigned short* gx    = (unsigned short*)p; p += (size_t)LL * BB * GG * 2;   // 134 MB
    unsigned int*   flags = (unsigned int*)p;   p += NTEAM * NDG * sizeof(unsigned int);

    hipMemsetAsync(flags, 0, NTEAM * NDG * sizeof(unsigned int), stream);
    build_x_kernel<<<dim3(2048), dim3(256), 0, stream>>>(act, inF, xb);
    cast_kernel<<<dim3(1024), dim3(256), 0, stream>>>(Wih, wih_b, GG * KK);
    cast_kernel<<<dim3(64), dim3(256), 0, stream>>>(h0, hb, BB * HH);
    gemm_x_kernel<<<dim3(128, 32), dim3(256), 0, stream>>>(xb, wih_b, gx);

    void* args[] = { (void*)&gx, (void*)&Whh, (void*)&bih, (void*)&bhh,
                     (void*)&c0, (void*)&hb, (void*)&flags, (void*)&out };
    hipLaunchCooperativeKernel((const void*)lstm_kernel, dim3(NBLK), dim3(512), args, 0, stream);
}

// Round 9
// 789.944 us; speedup vs baseline: 1.5737x; 1.2022x over previous
//
#include <hip/hip_runtime.h>
#include <hip/hip_bf16.h>

#define LL 128
#define BB 128
#define AA 512
#define II 512
#define HH 1024
#define GG 4096   // 4*H
#define KK 1024   // I+A (W_ih row length)
#define NTEAM 8   // 8 teams x 16 batches
#define NDG 32    // 32 dim-groups x 32 dims
#define NBLK (NTEAM * NDG)   // 256 blocks

typedef __attribute__((ext_vector_type(8))) short short8;
typedef __attribute__((ext_vector_type(4))) float f32x4;
typedef __attribute__((ext_vector_type(4))) unsigned uint32x4;

static __device__ __forceinline__ unsigned short f2b(float x) {
    union { float f; unsigned u; } v; v.f = x;
    unsigned r = v.u + 0x7fffu + ((v.u >> 16) & 1u);
    return (unsigned short)(r >> 16);
}
static __device__ __forceinline__ float fast_sigmoid(float x) {
    return 1.f / (1.f + __expf(-x));
}
static __device__ __forceinline__ float fast_tanh(float x) {
    float e = __expf(2.f * x);
    return (e - 1.f) / (e + 1.f);
}

// device-coherent UC accesses (proven rounds 4/7/8): bypass L1+L2, served at coherence point
static __device__ __forceinline__ short8 uc_load128(const unsigned short* p) {
    short8 r;
    asm volatile("global_load_dwordx4 %0, %1, off sc0 sc1" : "=v"(r) : "v"(p));
    return r;
}
static __device__ __forceinline__ void uc_store128(unsigned short* p, uint32x4 v) {
    asm volatile("global_store_dwordx4 %0, %1, off sc0 sc1" :: "v"(p), "v"(v) : "memory");
}
static __device__ __forceinline__ unsigned uc_flag_load(const unsigned int* p) {
    unsigned fv;
    asm volatile("global_load_dword %0, %1, off sc0 sc1\n\ts_waitcnt vmcnt(0)"
                 : "=v"(fv) : "v"(p) : "memory");
    return fv;
}
static __device__ __forceinline__ void uc_flag_store(unsigned int* p, unsigned v) {
    asm volatile("global_store_dword %0, %1, off sc0 sc1" :: "v"(p), "v"(v) : "memory");
}

// ---------------- pack kernels ----------------
__global__ void cast_kernel(const float* __restrict__ s, unsigned short* __restrict__ d, int n) {
    int stride = gridDim.x * blockDim.x;
    for (int i = blockIdx.x * blockDim.x + threadIdx.x; i < n; i += stride) d[i] = f2b(s[i]);
}

// ---------------- fused persistent LSTM (input projection folded in) ----------------
// 256 blocks = 8 teams (16 batches) x 32 dim-groups (32 dims).
//   W_hh slice (4g x 32d x 1024K bf16 = 256 KB) in REGISTERS (128 VGPR/thr).
//   W_a  slice (4g x 32d x  512K bf16 = 128 KB) in LDS, fragment order (wave-private regions).
//   base = W_x*inF + b_ih + b_hh computed once in prologue (all-wave MFMA + LDS reduce).
// Per step: acc = W_a*a_l (BEFORE the poll -> hidden in wait) + W_hh*h_{l-1} (after).
// Sync protocol identical to round 8: per-dg UC flags, single poller wave (w7),
// 2-buffer h ping-pong; h-store at step l gated by sync2 (all waves passed poll(l))
// so overwriting buf[(l+1)&1] is race-free.
__launch_bounds__(512, 2)
__global__ void lstm_kernel(const unsigned short* __restrict__ xa,   // [L*B][512] bf16 (action features)
                            const float* __restrict__ inF,           // [B][512] f32
                            const float* __restrict__ Wih,           // [4096][1024] f32
                            const float* __restrict__ Whh,           // [4096][1024] f32
                            const float* __restrict__ bih,
                            const float* __restrict__ bhh,
                            const float* __restrict__ c0,            // [B][H] f32
                            unsigned short* __restrict__ hb,         // [2][B][H] bf16
                            unsigned int* __restrict__ flagsG,       // [NTEAM*NDG] zeroed
                            float* __restrict__ out) {               // hs | h_n | c_n
    __shared__ __attribute__((aligned(16))) unsigned short wa_lds[8 * 16 * 64 * 8]; // 128 KB
    __shared__ float red[2 * 3 * 64 * 17];                                          // ~26 KB
    __shared__ __attribute__((aligned(16))) unsigned short hbuf[16 * 32];           // 1 KB

    const int tid  = threadIdx.x;
    const int lane = tid & 63;
    const int w    = tid >> 6;          // 8 waves
    const int nq   = w >> 2;            // dim-half (16 dims)
    const int ksl  = w & 3;             // K-slice
    const int dg   = blockIdx.x & (NDG - 1);
    const int mg   = blockIdx.x >> 5;   // team
    const int j0   = dg * 32;
    const int b0   = mg * 16;
    const int d    = lane & 15;
    const int rg   = lane >> 4;

    // ---- W_hh slice into registers, B-fragment order (K-slice 256 per wave) ----
    short8 breg[4][8];
    #pragma unroll
    for (int t = 0; t < 4; ++t) {
        #pragma unroll
        for (int kf = 0; kf < 8; ++kf) {
            const float* src = &Whh[(size_t)(t * HH + j0 + nq * 16 + d) * HH + ksl * 256 + kf * 32 + rg * 8];
            short8 v;
            #pragma unroll
            for (int j = 0; j < 8; ++j) v[j] = (short)f2b(src[j]);
            breg[t][kf] = v;
        }
    }

    // ---- W_a slice into LDS (wave-private region), fragment order (K-slice 128 per wave) ----
    #pragma unroll
    for (int t = 0; t < 4; ++t) {
        #pragma unroll
        for (int kf = 0; kf < 4; ++kf) {
            const float* src = &Wih[(size_t)(t * HH + j0 + nq * 16 + d) * KK + II + ksl * 128 + kf * 32 + rg * 8];
            unsigned short* dst = &wa_lds[(((size_t)w * 16 + t * 4 + kf) * 64 + lane) * 8];
            #pragma unroll
            for (int j = 0; j < 8; ++j) dst[j] = f2b(src[j]);
        }
    }

    // ---- base = W_x * inF (all-wave, K-slice 128 each) ----
    f32x4 bacc[4] = {};
    #pragma unroll
    for (int kf = 0; kf < 4; ++kf) {
        const float* xs = &inF[(size_t)(b0 + d) * II + ksl * 128 + kf * 32 + rg * 8];
        short8 xf;
        #pragma unroll
        for (int j = 0; j < 8; ++j) xf[j] = (short)f2b(xs[j]);
        #pragma unroll
        for (int t = 0; t < 4; ++t) {
            const float* ws = &Wih[(size_t)(t * HH + j0 + nq * 16 + d) * KK + ksl * 128 + kf * 32 + rg * 8];
            short8 wf;
            #pragma unroll
            for (int j = 0; j < 8; ++j) wf[j] = (short)f2b(ws[j]);
            bacc[t] = __builtin_amdgcn_mfma_f32_16x16x32_bf16(xf, wf, bacc[t], 0, 0, 0);
        }
    }
    if (ksl != 0) {
        float* sp = &red[(size_t)((nq * 3 + (ksl - 1)) * 64 + lane) * 17];
        #pragma unroll
        for (int t = 0; t < 4; ++t)
            #pragma unroll
            for (int r = 0; r < 4; ++r) sp[t * 4 + r] = bacc[t][r];
    }
    __syncthreads();
    float base_r[16], c_r[4];
    if (ksl == 0) {
        #pragma unroll
        for (int s = 0; s < 3; ++s) {
            const float* sp = &red[(size_t)((nq * 3 + s) * 64 + lane) * 17];
            #pragma unroll
            for (int t = 0; t < 4; ++t)
                #pragma unroll
                for (int r = 0; r < 4; ++r) bacc[t][r] += sp[t * 4 + r];
        }
        #pragma unroll
        for (int t = 0; t < 4; ++t) {
            float bias = bih[t * HH + j0 + nq * 16 + d] + bhh[t * HH + j0 + nq * 16 + d];
            #pragma unroll
            for (int r = 0; r < 4; ++r) base_r[t * 4 + r] = bacc[t][r] + bias;
        }
        #pragma unroll
        for (int r = 0; r < 4; ++r) c_r[r] = c0[(b0 + rg * 4 + r) * HH + j0 + nq * 16 + d];
    }
    __syncthreads();   // red free for the step loop

    unsigned int*       ourflag  = flagsG + mg * NDG + dg;
    const unsigned int* pollflag = flagsG + mg * NDG + (lane & 31);

    for (int l = 0; l < LL; ++l) {
        const unsigned short* hr = hb + (size_t)(l & 1) * (BB * HH);
        unsigned short*       hw = hb + (size_t)((l + 1) & 1) * (BB * HH);

        // ---- input projection W_a * a_l: no h dependency, hides inside the poll wait ----
        f32x4 acc[4] = {};
        {
            const unsigned short* ap = xa + ((size_t)l * BB + b0 + d) * AA + ksl * 128 + rg * 8;
            short8 aaf[4];
            #pragma unroll
            for (int kf = 0; kf < 4; ++kf) aaf[kf] = *(const short8*)(ap + kf * 32);
            #pragma unroll
            for (int kf = 0; kf < 4; ++kf)
                #pragma unroll
                for (int t = 0; t < 4; ++t) {
                    short8 wfr = *(const short8*)&wa_lds[(((size_t)w * 16 + t * 4 + kf) * 64 + lane) * 8];
                    acc[t] = __builtin_amdgcn_mfma_f32_16x16x32_bf16(aaf[kf], wfr, acc[t], 0, 0, 0);
                }
        }

        // single-poller: wave 7, one wave-wide UC load of all 32 team flags per spin
        if (l > 0 && w == 7) {
            unsigned fv; int guard = 0;
            do { fv = uc_flag_load(pollflag); }
            while (__any(fv < (unsigned)l) && ++guard < (1 << 18));
        }
        __syncthreads();   // releases all waves once flags are seen

        // ---- coherent h read + recurrent GEMM (accumulates into acc) ----
        short8 af[8];
        const unsigned short* hp = hr + (size_t)(b0 + d) * HH + ksl * 256 + rg * 8;
        #pragma unroll
        for (int kf = 0; kf < 8; ++kf) af[kf] = uc_load128(hp + kf * 32);
        asm volatile("s_waitcnt vmcnt(0)" ::: "memory");
        __builtin_amdgcn_sched_barrier(0);

        #pragma unroll
        for (int kf = 0; kf < 8; ++kf)
            #pragma unroll
            for (int t = 0; t < 4; ++t)
                acc[t] = __builtin_amdgcn_mfma_f32_16x16x32_bf16(af[kf], breg[t][kf], acc[t], 0, 0, 0);

        // single-round cross-wave K reduction: ksl 1..3 write, sync, ksl 0 absorbs
        if (ksl != 0) {
            float* sp = &red[(size_t)((nq * 3 + (ksl - 1)) * 64 + lane) * 17];
            #pragma unroll
            for (int t = 0; t < 4; ++t)
                #pragma unroll
                for (int r = 0; r < 4; ++r) sp[t * 4 + r] = acc[t][r];
        }
        __syncthreads();   // sync1: partials ready

        if (ksl == 0) {
            #pragma unroll
            for (int s = 0; s < 3; ++s) {
                const float* sp = &red[(size_t)((nq * 3 + s) * 64 + lane) * 17];
                #pragma unroll
                for (int t = 0; t < 4; ++t)
                    #pragma unroll
                    for (int r = 0; r < 4; ++r) acc[t][r] += sp[t * 4 + r];
            }
            #pragma unroll
            for (int r = 0; r < 4; ++r) {
                float gi = acc[0][r] + base_r[0 + r];
                float gf = acc[1][r] + base_r[4 + r];
                float gg = acc[2][r] + base_r[8 + r];
                float go = acc[3][r] + base_r[12 + r];
                float ig = fast_sigmoid(gi);
                float fg = fast_sigmoid(gf);
                float og = fast_sigmoid(go);
                float gt = fast_tanh(gg);
                float c1 = fg * c_r[r] + ig * gt;
                float h1 = og * fast_tanh(c1);
                c_r[r] = c1;
                hbuf[(rg * 4 + r) * 32 + nq * 16 + d] = f2b(h1);
                out[((size_t)l * BB + (b0 + rg * 4 + r)) * HH + j0 + nq * 16 + d] = h1;
                if (l == LL - 1) {
                    out[(size_t)LL * BB * HH + (b0 + rg * 4 + r) * HH + j0 + nq * 16 + d] = h1;
                    out[(size_t)LL * BB * HH + BB * HH + (b0 + rg * 4 + r) * HH + j0 + nq * 16 + d] = c1;
                }
            }
        }
        __syncthreads();   // sync2: hbuf ready, red consumed, all polls passed

        // wave 2 (non-gate): line-dense h store (16 batches x 64 B) + flag
        if (w == 2) {
            int row = lane >> 2, ch = lane & 3;
            uint32x4 hv = *(const uint32x4*)&hbuf[row * 32 + ch * 8];
            uc_store128(&hw[(size_t)(b0 + row) * HH + j0 + ch * 8], hv);
            asm volatile("s_waitcnt vmcnt(0)" ::: "memory");   // acked at coherence point
            if (lane == 0) uc_flag_store(ourflag, (unsigned)(l + 1));
        }
    }
}

extern "C" void kernel_launch(void* const* d_in, const int* in_sizes, int n_in,
                              void* d_out, int out_size, void* d_ws, size_t ws_size,
                              hipStream_t stream) {
    const float* act = (const float*)d_in[0];
    const float* inF = (const float*)d_in[1];
    const float* h0  = (const float*)d_in[2];
    const float* c0  = (const float*)d_in[3];
    const float* Wih = (const float*)d_in[4];
    const float* Whh = (const float*)d_in[5];
    const float* bih = (const float*)d_in[6];
    const float* bhh = (const float*)d_in[7];
    float* out = (float*)d_out;

    char* p = (char*)d_ws;
    unsigned short* xa    = (unsigned short*)p; p += (size_t)LL * BB * AA * 2;   // 16.8 MB
    unsigned short* hb    = (unsigned short*)p; p += (size_t)2 * BB * HH * 2;    //  0.5 MB
    unsigned int*   flags = (unsigned int*)p;   p += NTEAM * NDG * sizeof(unsigned int);

    hipMemsetAsync(flags, 0, NTEAM * NDG * sizeof(unsigned int), stream);
    cast_kernel<<<dim3(2048), dim3(256), 0, stream>>>(act, xa, LL * BB * AA);
    cast_kernel<<<dim3(64), dim3(256), 0, stream>>>(h0, hb, BB * HH);

    void* args[] = { (void*)&xa, (void*)&inF, (void*)&Wih, (void*)&Whh, (void*)&bih,
                     (void*)&bhh, (void*)&c0, (void*)&hb, (void*)&flags, (void*)&out };
    hipLaunchCooperativeKernel((const void*)lstm_kernel, dim3(NBLK), dim3(512), args, 0, stream);
}